// Round 7
// baseline (27.514 us; speedup 1.0000x reference)
//
#include <hip/hip_runtime.h>
#include <math.h>

// 32 fixed taps from the problem definition (TAPS_INT), as exact fp32 values.
__device__ __constant__ const float TAPS[32] = {
    -12.f,  -34.f,  -56.f,  -42.f,   18.f,  120.f,  260.f,  380.f,
    400.f,  290.f,   60.f, -210.f, -430.f, -500.f, -380.f, -120.f,
    180.f,  430.f,  540.f,  480.f,  280.f,   20.f, -220.f, -370.f,
   -400.f, -310.f, -150.f,   10.f,  120.f,  160.f,  130.f,   60.f
};

#define SCALE_INV (1.0f / 65536.0f)
#define NT_BLOCKS 2048
#define NT_THREADS 256

// Native clang vector type: __builtin_nontemporal_store requires it
// (HIP_vector_type<float,4> is a struct and is rejected).
typedef float floatx4 __attribute__((ext_vector_type(4)));

// Persistent grid-stride: 2048 blocks x 256 threads (8 waves/SIMD resident
// once, no wave-relaunch ramp), each thread sweeps 4 chunks of 8 outputs.
// Loads of chunk i+1 overlap FMAs/stores of chunk i inside the wave.
// Non-temporal stores: y is never re-read, keep L2/L3 for the x stream.
__global__ __launch_bounds__(NT_THREADS)
void fir32_persist(const float* __restrict__ x, float* __restrict__ y, int n) {
    const long nchunks = (long)n >> 3;                       // 8 outputs per chunk
    const long stride = (long)NT_BLOCKS * NT_THREADS;        // threads in grid
    const long gtid = (long)blockIdx.x * NT_THREADS + threadIdx.x;

    const floatx4* x4 = reinterpret_cast<const floatx4*>(x);
    floatx4* y4 = reinterpret_cast<floatx4*>(y);

    for (long c = gtid; c < nchunks; c += stride) {
        const long o4 = 2L * c;                              // first output float4
        const bool head = (c < 4);                           // outputs 0..31 == 0

        // Window x[8c-32 .. 8c+7] = float4 indices o4-8 .. o4+1 (clamped only
        // for the 4 head chunks, whose results are predicated to zero anyway).
        float w[40];
        #pragma unroll
        for (int q = 0; q < 10; ++q) {
            long i4 = o4 - 8 + q;
            i4 = (i4 < 0) ? 0 : i4;
            floatx4 v = x4[i4];
            w[4 * q + 0] = v.x;
            w[4 * q + 1] = v.y;
            w[4 * q + 2] = v.z;
            w[4 * q + 3] = v.w;
        }

        float acc[8];
        #pragma unroll
        for (int j = 0; j < 8; ++j) {
            float a = 0.0f;
            #pragma unroll
            for (int k = 0; k < 32; ++k) {
                // y[8c + j] needs x[m-k] == w[32 + j - k]
                a = fmaf(w[32 + j - k], TAPS[k], a);
            }
            acc[j] = head ? 0.0f : floorf(a * SCALE_INV);
        }

        floatx4 out0 = { acc[0], acc[1], acc[2], acc[3] };
        floatx4 out1 = { acc[4], acc[5], acc[6], acc[7] };
        __builtin_nontemporal_store(out0, &y4[o4]);
        __builtin_nontemporal_store(out1, &y4[o4 + 1]);
    }
}

extern "C" void kernel_launch(void* const* d_in, const int* in_sizes, int n_in,
                              void* d_out, int out_size, void* d_ws, size_t ws_size,
                              hipStream_t stream) {
    const float* x = (const float*)d_in[0];
    float* y = (float*)d_out;
    const int n = in_sizes[0];

    fir32_persist<<<dim3(NT_BLOCKS), dim3(NT_THREADS), 0, stream>>>(x, y, n);
}